// Round 2
// baseline (11160.026 us; speedup 1.0000x reference)
//
#include <hip/hip_runtime.h>

// ---------------- helpers ----------------
__device__ __forceinline__ float sigm(float x) {
    return 1.0f / (1.0f + __expf(-x));
}
__device__ __forceinline__ float tanh_(float x) {
    return 1.0f - 2.0f / (1.0f + __expf(2.0f * x));
}
__device__ __forceinline__ unsigned int packbf2(float a, float b) {
    unsigned int ua = __float_as_uint(a);
    ua = (ua + 0x7fffu + ((ua >> 16) & 1u)) >> 16;
    unsigned int ub = __float_as_uint(b);
    ub = (ub + 0x7fffu + ((ub >> 16) & 1u)) >> 16;
    return ua | (ub << 16);
}

// ---------------- LSTM layer 1 (bidirectional, fused input projection K=40) ----------------
// grid 128: blocks 0..63 = fwd batch b, 64..127 = rev batch b. block 512 threads.
__global__ __launch_bounds__(512) void lstm1_k(
    const float* __restrict__ utter,
    const float* __restrict__ wih_f, const float* __restrict__ whh_f,
    const float* __restrict__ bih_f, const float* __restrict__ bhh_f,
    const float* __restrict__ wih_r, const float* __restrict__ whh_r,
    const float* __restrict__ bih_r, const float* __restrict__ bhh_r,
    float* __restrict__ Hf, float* __restrict__ Hr)
{
    const int tid = threadIdx.x;
    const int b   = blockIdx.x & 63;
    const int dir = blockIdx.x >> 6;
    const float* wih = dir ? wih_r : wih_f;
    const float* whh = dir ? whh_r : whh_f;
    const float* bih = dir ? bih_r : bih_f;
    const float* bhh = dir ? bhh_r : bhh_f;
    float* Hout = dir ? Hr : Hf;

    __shared__ __align__(16) float h_lds[128];
    __shared__ float gates[512];
    __shared__ __align__(16) float x3[3][48];

    const int j = tid;
    float4 wr[32];
    {
        const float4* wp = reinterpret_cast<const float4*>(whh + j * 128);
#pragma unroll
        for (int m = 0; m < 32; ++m) wr[m] = wp[m];
    }
    float4 wx[10];
    {
        const float4* xp = reinterpret_cast<const float4*>(wih + j * 40);
#pragma unroll
        for (int q = 0; q < 10; ++q) wx[q] = xp[q];
    }
    const float bias = bih[j] + bhh[j];
    float c = 0.0f;
    if (tid < 128) h_lds[tid] = 0.0f;
    if (tid < 40) {
        int tt0 = dir ? 2047 : 0;
        x3[0][tid] = utter[((size_t)b * 2048 + tt0) * 40 + tid];
    } else if (tid < 80) {
        int tt1 = dir ? 2046 : 1;
        x3[1][tid - 40] = utter[((size_t)b * 2048 + tt1) * 40 + (tid - 40)];
    }
    __syncthreads();

    for (int t = 0; t < 2048; ++t) {
        const int cur = t % 3;
        const int nx2 = (t + 2) % 3;
        float xn = 0.0f;
        const int tq = tid - 128;
        if (tq >= 0 && tq < 40) {
            int tn = (t + 2 < 2048) ? (t + 2) : 2047;
            int ttn = dir ? (2047 - tn) : tn;
            xn = utter[((size_t)b * 2048 + ttn) * 40 + tq];  // prefetch depth-2
        }
        float g = bias;
        const float4* x4 = reinterpret_cast<const float4*>(&x3[cur][0]);
#pragma unroll
        for (int q = 0; q < 10; ++q) {
            float4 x = x4[q];
            g += wx[q].x * x.x + wx[q].y * x.y + wx[q].z * x.z + wx[q].w * x.w;
        }
        const float4* h4 = reinterpret_cast<const float4*>(h_lds);
#pragma unroll
        for (int m = 0; m < 32; ++m) {
            float4 h = h4[m];
            g += wr[m].x * h.x + wr[m].y * h.y + wr[m].z * h.z + wr[m].w * h.w;
        }
        gates[j] = g;
        __syncthreads();
        if (tid < 128) {
            float i_ = sigm(gates[tid]);
            float f_ = sigm(gates[128 + tid]);
            float g_ = tanh_(gates[256 + tid]);
            float o_ = sigm(gates[384 + tid]);
            c = f_ * c + i_ * g_;
            float hh = o_ * tanh_(c);
            h_lds[tid] = hh;
            int tt = dir ? (2047 - t) : t;
            Hout[((size_t)tt * 64 + b) * 128 + tid] = hh;
        } else if (tq < 40) {
            x3[nx2][tq] = xn;
        }
        __syncthreads();
    }
}

// ---------------- LSTM layers 2/3 (P precomputed incl. biases) ----------------
__global__ __launch_bounds__(512) void lstm_k(
    const float* __restrict__ P, const float* __restrict__ whh,
    float* __restrict__ Hout, int T)
{
    const int tid = threadIdx.x;
    const int b = blockIdx.x;
    const int j = tid;
    __shared__ __align__(16) float h_lds[128];
    __shared__ float gates[512];
    float4 wr[32];
    {
        const float4* wp = reinterpret_cast<const float4*>(whh + j * 128);
#pragma unroll
        for (int m = 0; m < 32; ++m) wr[m] = wp[m];
    }
    float c = 0.0f;
    if (tid < 128) h_lds[tid] = 0.0f;
    float p_cur = P[((size_t)b * T + 0) * 512 + j];
    float p_n1  = P[((size_t)b * T + ((T > 1) ? 1 : 0)) * 512 + j];
    __syncthreads();
    for (int t = 0; t < T; ++t) {
        int tn = (t + 2 < T) ? (t + 2) : (T - 1);
        float p_n2 = P[((size_t)b * T + tn) * 512 + j];  // prefetch depth-2
        float g = p_cur;
        const float4* h4 = reinterpret_cast<const float4*>(h_lds);
#pragma unroll
        for (int m = 0; m < 32; ++m) {
            float4 h = h4[m];
            g += wr[m].x * h.x + wr[m].y * h.y + wr[m].z * h.z + wr[m].w * h.w;
        }
        gates[j] = g;
        __syncthreads();
        if (tid < 128) {
            float i_ = sigm(gates[tid]);
            float f_ = sigm(gates[128 + tid]);
            float g_ = tanh_(gates[256 + tid]);
            float o_ = sigm(gates[384 + tid]);
            c = f_ * c + i_ * g_;
            float hh = o_ * tanh_(c);
            h_lds[tid] = hh;
            Hout[((size_t)t * 64 + b) * 128 + tid] = hh;
        }
        __syncthreads();
        p_cur = p_n1;
        p_n1 = p_n2;
    }
}

// ---------------- conv1d kernel=2 stride=2 (as feature-pair dot) ----------------
// grid (B, Tout/32), block 128 (thread = out channel). H layout: [t][b][128].
template <int CIN>
__global__ __launch_bounds__(128) void conv_k(
    const float* __restrict__ HA, const float* __restrict__ HB,
    const float* __restrict__ W, const float* __restrict__ bias,
    float* __restrict__ out, int Tout)
{
    __shared__ __align__(16) float xin[64 * CIN];
    const int b = blockIdx.x;
    const int t0 = blockIdx.y * 32;
    const int tid = threadIdx.x;
    for (int idx = tid; idx < 64 * CIN; idx += 128) {
        int tl = idx / CIN, ci = idx % CIN;
        int tau = t0 * 2 + tl;
        float v;
        if constexpr (CIN == 256) {
            v = (ci < 128) ? HA[(size_t)tau * 8192 + b * 128 + ci]
                           : HB[(size_t)tau * 8192 + b * 128 + (ci - 128)];
        } else {
            v = HA[(size_t)tau * 8192 + b * 128 + ci];
        }
        xin[idx] = v;
    }
    __syncthreads();
    const int co = tid;
    float acc[32];
#pragma unroll
    for (int u = 0; u < 32; ++u) acc[u] = 0.0f;
    const float4* Wrow4 = reinterpret_cast<const float4*>(W + (size_t)co * 2 * CIN);
    const float4* xin4 = reinterpret_cast<const float4*>(xin);
    for (int c4 = 0; c4 < CIN / 4; ++c4) {
        float4 wA = Wrow4[2 * c4];
        float4 wB = Wrow4[2 * c4 + 1];
#pragma unroll
        for (int u = 0; u < 32; ++u) {
            float4 x0 = xin4[(2 * u) * (CIN / 4) + c4];
            float4 x1 = xin4[(2 * u + 1) * (CIN / 4) + c4];
            acc[u] += wA.x * x0.x + wA.y * x1.x + wA.z * x0.y + wA.w * x1.y
                    + wB.x * x0.z + wB.y * x1.z + wB.z * x0.w + wB.w * x1.w;
        }
    }
    float bs = bias[co];
#pragma unroll
    for (int u = 0; u < 32; ++u)
        out[((size_t)b * Tout + t0 + u) * 128 + co] = acc[u] + bs;
}

// ---------------- generic f32 GEMM: C[m,n] = sum_k A[m,k]*W[n,k] + b1[n] + b2[n] ----------------
// mode 0: C[m*N+n]; mode 1: m=(t*64+b) -> C[(b*N+n)*Tdim + t]  (transposed per-batch store)
__global__ __launch_bounds__(256) void gemm_k(
    const float* __restrict__ A, const float* __restrict__ W, int ldw,
    const float* __restrict__ bias1, const float* __restrict__ bias2,
    float* __restrict__ C, int M, int N, int K, int mode, int Tdim)
{
    __shared__ __align__(16) float As[16][68];
    __shared__ __align__(16) float Ws[16][68];
    const int tid = threadIdx.x;
    const int m0 = blockIdx.x * 64, n0 = blockIdx.y * 64;
    const int kk = tid & 15, mm = tid >> 4;
    const int tm = tid & 15, tn = tid >> 4;
    float acc[4][4];
#pragma unroll
    for (int i = 0; i < 4; ++i)
#pragma unroll
        for (int jj = 0; jj < 4; ++jj) acc[i][jj] = 0.0f;

    for (int k0 = 0; k0 < K; k0 += 16) {
#pragma unroll
        for (int r = 0; r < 4; ++r) {
            As[kk][mm + 16 * r] = A[(size_t)(m0 + mm + 16 * r) * K + k0 + kk];
            Ws[kk][mm + 16 * r] = W[(size_t)(n0 + mm + 16 * r) * ldw + k0 + kk];
        }
        __syncthreads();
#pragma unroll
        for (int q = 0; q < 16; ++q) {
            float4 a = reinterpret_cast<const float4*>(&As[q][0])[tm];
            float4 w = reinterpret_cast<const float4*>(&Ws[q][0])[tn];
            acc[0][0] += a.x * w.x; acc[0][1] += a.x * w.y; acc[0][2] += a.x * w.z; acc[0][3] += a.x * w.w;
            acc[1][0] += a.y * w.x; acc[1][1] += a.y * w.y; acc[1][2] += a.y * w.z; acc[1][3] += a.y * w.w;
            acc[2][0] += a.z * w.x; acc[2][1] += a.z * w.y; acc[2][2] += a.z * w.z; acc[2][3] += a.z * w.w;
            acc[3][0] += a.w * w.x; acc[3][1] += a.w * w.y; acc[3][2] += a.w * w.z; acc[3][3] += a.w * w.w;
        }
        __syncthreads();
    }
    float bv[4];
#pragma unroll
    for (int jj = 0; jj < 4; ++jj) {
        int n = n0 + tn * 4 + jj;
        float v = 0.0f;
        if (bias1) v += bias1[n];
        if (bias2) v += bias2[n];
        bv[jj] = v;
    }
#pragma unroll
    for (int i = 0; i < 4; ++i) {
        int m = m0 + tm * 4 + i;
#pragma unroll
        for (int jj = 0; jj < 4; ++jj) {
            int n = n0 + tn * 4 + jj;
            float v = acc[i][jj] + bv[jj];
            if (mode == 0) {
                C[(size_t)m * N + n] = v;
            } else {
                int bb = m & 63, tt = m >> 6;
                C[((size_t)bb * N + n) * Tdim + tt] = v;
            }
        }
    }
}

// ---------------- gather emb[targets] rows: Ypack[(l*64+b)][e] ----------------
__global__ __launch_bounds__(512) void packemb_k(
    const int* __restrict__ targets, const float* __restrict__ emb,
    float* __restrict__ Ypack)
{
    int m = blockIdx.x;  // l*64 + b
    int l = m >> 6, b = m & 63;
    int tgt = targets[b * 256 + l];
    Ypack[(size_t)m * 512 + threadIdx.x] = emb[(size_t)tgt * 512 + threadIdx.x];
}

// ---------------- attention decoder: one WG per batch, 255 steps ----------------
__global__ __launch_bounds__(512) void decoder_k(
    const float* __restrict__ Yp, const float* __restrict__ whhd, const float* __restrict__ wihd,
    const float* __restrict__ hkT, const float* __restrict__ hv,
    const float* __restrict__ w1, const float* __restrict__ b1,
    const float* __restrict__ w2, const float* __restrict__ b2,
    const float* __restrict__ w3, const float* __restrict__ b3,
    const float* __restrict__ sh0, const float* __restrict__ sc0,
    float* __restrict__ out)
{
    __shared__ unsigned int wc2[64][512];  // 128 KiB: c-path weights, bf16 pairs, [k2][j]
    __shared__ __align__(16) float sh_lds[128];
    __shared__ __align__(16) float sc_lds[128];
    __shared__ __align__(16) float c_lds[128];
    __shared__ float gates[512];
    __shared__ float att[512];
    __shared__ float red[16];
    __shared__ float out_lds[34];
    __shared__ float z_lds[34];

    const int tid = threadIdx.x;
    const int b = blockIdx.x;
    const int j = tid;

    float4 wr[32];
    {
        const float4* wp = reinterpret_cast<const float4*>(whhd + j * 128);
#pragma unroll
        for (int m = 0; m < 32; ++m) wr[m] = wp[m];
    }
    for (int idx = tid; idx < 64 * 512; idx += 512) {
        int k2 = idx >> 9, jj = idx & 511;
        float a = wihd[(size_t)jj * 640 + 512 + 2 * k2];
        float bb2 = wihd[(size_t)jj * 640 + 512 + 2 * k2 + 1];
        wc2[k2][jj] = packbf2(a, bb2);
    }
    float sc_r = 0.0f;
    if (tid < 128) {
        sh_lds[tid] = sh0[b * 128 + tid];
        sc_r = sc0[b * 128 + tid];
        sc_lds[tid] = sc_r;
        c_lds[tid] = 0.0f;
    }
    __syncthreads();

    const int wid = tid >> 6, lane = tid & 63;
    float yp_cur = Yp[(size_t)(0 * 64 + b) * 512 + j];
    for (int l = 0; l < 255; ++l) {
        int lnxt = (l + 1 < 255) ? (l + 1) : l;
        float yp_nxt = Yp[(size_t)(lnxt * 64 + b) * 512 + j];
        // ---- phase 1: gates = Yp + sh@whhd.T + c@wihd_c.T
        float g = yp_cur;
        const float4* sh4 = reinterpret_cast<const float4*>(sh_lds);
#pragma unroll
        for (int m = 0; m < 32; ++m) {
            float4 h = sh4[m];
            g += wr[m].x * h.x + wr[m].y * h.y + wr[m].z * h.z + wr[m].w * h.w;
        }
        const float2* c2 = reinterpret_cast<const float2*>(c_lds);
#pragma unroll
        for (int k2 = 0; k2 < 64; ++k2) {
            unsigned int u = wc2[k2][j];
            float2 cc = c2[k2];
            g += __uint_as_float(u << 16) * cc.x + __uint_as_float(u & 0xffff0000u) * cc.y;
        }
        gates[j] = g;
        __syncthreads();
        // ---- phase 2: cell update
        if (tid < 128) {
            float i_ = sigm(gates[tid]);
            float f_ = sigm(gates[128 + tid]);
            float g_ = tanh_(gates[256 + tid]);
            float o_ = sigm(gates[384 + tid]);
            sc_r = f_ * sc_r + i_ * g_;
            float hh = o_ * tanh_(sc_r);
            sh_lds[tid] = hh;
            sc_lds[tid] = sc_r;
        }
        __syncthreads();
        // ---- phase 3: attention scores over 512 positions (attends with sc_n)
        float e = 0.0f;
        {
            const float* hp = hkT + (size_t)b * 65536 + tid;
#pragma unroll 4
            for (int d = 0; d < 128; ++d) e += hp[(size_t)d * 512] * sc_lds[d];
        }
        float em = e;
#pragma unroll
        for (int off = 32; off; off >>= 1) em = fmaxf(em, __shfl_xor(em, off));
        if (lane == 0) red[wid] = em;
        __syncthreads();
        float mx = red[0];
#pragma unroll
        for (int w = 1; w < 8; ++w) mx = fmaxf(mx, red[w]);
        float p = __expf(e - mx);
        float ps = p;
#pragma unroll
        for (int off = 32; off; off >>= 1) ps += __shfl_xor(ps, off);
        if (lane == 0) red[8 + wid] = ps;
        __syncthreads();
        float S = red[8];
#pragma unroll
        for (int w = 1; w < 8; ++w) S += red[8 + w];
        att[tid] = p / S;
        __syncthreads();
        // ---- phase 4: context c_n = att @ hv
        {
            int g4 = tid >> 7, d = tid & 127;
            const float* hvp = hv + (size_t)b * 128 + d;
            float acc = 0.0f;
            int tbase = g4 * 128;
#pragma unroll 4
            for (int tt = 0; tt < 128; ++tt)
                acc += att[tbase + tt] * hvp[(size_t)(tbase + tt) * 8192];
            gates[tid] = acc;
        }
        __syncthreads();
        if (tid < 128)
            c_lds[tid] = gates[tid] + gates[128 + tid] + gates[256 + tid] + gates[384 + tid];
        __syncthreads();
        // ---- phase 5: output head
        if (tid < 34) {
            float o1 = b1[tid] + b2[tid];
            const float* w1r = w1 + tid * 128;
            const float* w2r = w2 + tid * 128;
#pragma unroll 4
            for (int d = 0; d < 128; ++d) o1 += sh_lds[d] * w1r[d] + c_lds[d] * w2r[d];
            out_lds[tid] = fmaxf(o1, 0.0f);
        }
        __syncthreads();
        if (tid < 34) {
            float z = b3[tid];
            const float* w3r = w3 + tid * 34;
            for (int v = 0; v < 34; ++v) z += out_lds[v] * w3r[v];
            z_lds[tid] = z;
        }
        __syncthreads();
        if (tid < 34) {
            float zm = z_lds[0];
            for (int v = 1; v < 34; ++v) zm = fmaxf(zm, z_lds[v]);
            float Ssum = 0.0f;
            for (int v = 0; v < 34; ++v) Ssum += __expf(z_lds[v] - zm);
            out[((size_t)b * 255 + l) * 34 + tid] = __expf(z_lds[tid] - zm) / Ssum;
        }
        yp_cur = yp_nxt;
        __syncthreads();
    }
}

// ---------------- launch ----------------
extern "C" void kernel_launch(void* const* d_in, const int* in_sizes, int n_in,
                              void* d_out, int out_size, void* d_ws, size_t ws_size,
                              hipStream_t stream) {
    (void)in_sizes; (void)n_in; (void)out_size; (void)ws_size;
    const float* utter = (const float*)d_in[0];
    const int*   targets = (const int*)d_in[1];
    const float* wih_f = (const float*)d_in[2];
    const float* whh_f = (const float*)d_in[3];
    const float* bih_f = (const float*)d_in[4];
    const float* bhh_f = (const float*)d_in[5];
    const float* wih_r = (const float*)d_in[6];
    const float* whh_r = (const float*)d_in[7];
    const float* bih_r = (const float*)d_in[8];
    const float* bhh_r = (const float*)d_in[9];
    const float* c1w = (const float*)d_in[10];
    const float* c1b = (const float*)d_in[11];
    const float* wih1 = (const float*)d_in[12];
    const float* whh1 = (const float*)d_in[13];
    const float* bih1 = (const float*)d_in[14];
    const float* bhh1 = (const float*)d_in[15];
    const float* c2w = (const float*)d_in[16];
    const float* c2b = (const float*)d_in[17];
    const float* wih2 = (const float*)d_in[18];
    const float* whh2 = (const float*)d_in[19];
    const float* bih2 = (const float*)d_in[20];
    const float* bhh2 = (const float*)d_in[21];
    const float* kw = (const float*)d_in[22];
    const float* kb = (const float*)d_in[23];
    const float* vw = (const float*)d_in[24];
    const float* vb = (const float*)d_in[25];
    const float* wihd = (const float*)d_in[26];
    const float* whhd = (const float*)d_in[27];
    const float* bihd = (const float*)d_in[28];
    const float* bhhd = (const float*)d_in[29];
    const float* w1 = (const float*)d_in[30];
    const float* b1 = (const float*)d_in[31];
    const float* w2 = (const float*)d_in[32];
    const float* b2 = (const float*)d_in[33];
    const float* w3 = (const float*)d_in[34];
    const float* b3 = (const float*)d_in[35];
    const float* emb = (const float*)d_in[36];
    const float* sh0 = (const float*)d_in[37];
    const float* sc0 = (const float*)d_in[38];

    // ---- workspace plan, peak 160 MiB (phase-based reuse, stream-ordered) ----
    char* ws = (char*)d_ws;
    const size_t MB = 1ull << 20;
    float* Hf       = (float*)(ws + 0);         // 64 MiB  [t][b][128]
    float* Hr       = (float*)(ws + 64 * MB);   // 64 MiB  [t][b][128]
    float* conv1out = (float*)(ws + 128 * MB);  // 32 MiB  [b][t'][128]
    float* P2       = (float*)(ws + 0);         // 128 MiB [b][t'][512]   (over Hf+Hr)
    float* H2       = (float*)(ws + 128 * MB);  // 32 MiB  [t][b][128]    (over conv1out)
    float* conv2out = (float*)(ws + 0);         // 16 MiB  [b][t''][128]  (over P2 head)
    float* P3       = (float*)(ws + 16 * MB);   // 64 MiB  [b][t''][512]
    float* H3       = (float*)(ws + 80 * MB);   // 16 MiB  [t''][b][128]
    float* hkT      = (float*)(ws + 96 * MB);   // 16 MiB  [b][d][t'']
    float* hvb      = (float*)(ws + 112 * MB);  // 16 MiB  [t''][b][d]
    float* Ypack    = (float*)(ws + 128 * MB);  // 32 MiB  (over H2, dead after conv2)
    float* Yp       = (float*)(ws + 0);         // 32 MiB  (over conv2out+P3 head, dead after lstm3)

    // encoder layer 1 (bidirectional, fused input proj)
    lstm1_k<<<128, 512, 0, stream>>>(utter, wih_f, whh_f, bih_f, bhh_f,
                                     wih_r, whh_r, bih_r, bhh_r, Hf, Hr);
    // conv1: 256ch -> 128ch, T 2048 -> 1024
    conv_k<256><<<dim3(64, 32), 128, 0, stream>>>(Hf, Hr, c1w, c1b, conv1out, 1024);
    // input proj for lstm2 (writes over Hf/Hr, reads conv1out)
    gemm_k<<<dim3(1024, 8), 256, 0, stream>>>(conv1out, wih1, 128, bih1, bhh1,
                                              P2, 65536, 512, 128, 0, 0);
    lstm_k<<<64, 512, 0, stream>>>(P2, whh1, H2, 1024);
    // conv2: 128ch -> 128ch, T 1024 -> 512 (writes over P2 head, reads H2)
    conv_k<128><<<dim3(64, 16), 128, 0, stream>>>(H2, nullptr, c2w, c2b, conv2out, 512);
    gemm_k<<<dim3(512, 8), 256, 0, stream>>>(conv2out, wih2, 128, bih2, bhh2,
                                             P3, 32768, 512, 128, 0, 0);
    lstm_k<<<64, 512, 0, stream>>>(P3, whh2, H3, 512);
    // hk (transposed store), hv
    gemm_k<<<dim3(512, 2), 256, 0, stream>>>(H3, kw, 128, kb, nullptr,
                                             hkT, 32768, 128, 128, 1, 512);
    gemm_k<<<dim3(512, 2), 256, 0, stream>>>(H3, vw, 128, vb, nullptr,
                                             hvb, 32768, 128, 128, 0, 0);
    // decoder y-path projection (sequentially dead -> hoisted); Ypack over H2 (dead)
    packemb_k<<<16320, 512, 0, stream>>>(targets, emb, Ypack);
    gemm_k<<<dim3(255, 8), 256, 0, stream>>>(Ypack, wihd, 640, bihd, bhhd,
                                             Yp, 16320, 512, 512, 0, 0);
    // attention decoder
    decoder_k<<<64, 512, 0, stream>>>(Yp, whhd, wihd, hkT, hvb,
                                      w1, b1, w2, b2, w3, b3, sh0, sc0,
                                      (float*)d_out);
}

// Round 3
// 10372.371 us; speedup vs baseline: 1.0759x; 1.0759x over previous
//
#include <hip/hip_runtime.h>

// ---------------- helpers ----------------
__device__ __forceinline__ float sigm(float x) {
    return 1.0f / (1.0f + __expf(-x));
}
__device__ __forceinline__ float tanh_(float x) {
    return 1.0f - 2.0f / (1.0f + __expf(2.0f * x));
}
__device__ __forceinline__ unsigned int packbf2(float a, float b) {
    unsigned int ua = __float_as_uint(a);
    ua = (ua + 0x7fffu + ((ua >> 16) & 1u)) >> 16;
    unsigned int ub = __float_as_uint(b);
    ub = (ub + 0x7fffu + ((ub >> 16) & 1u)) >> 16;
    return ua | (ub << 16);
}

// ---------------- LSTM layer 1 (bidirectional, fused input projection K=40) ----------------
// grid 128: blocks 0..63 = fwd batch b, 64..127 = rev batch b. block 512 threads.
// launch_bounds(512,2): 2 waves/EU -> 256 VGPR cap so wr[32]+wx[10] stay in registers.
__global__ __launch_bounds__(512, 2) void lstm1_k(
    const float* __restrict__ utter,
    const float* __restrict__ wih_f, const float* __restrict__ whh_f,
    const float* __restrict__ bih_f, const float* __restrict__ bhh_f,
    const float* __restrict__ wih_r, const float* __restrict__ whh_r,
    const float* __restrict__ bih_r, const float* __restrict__ bhh_r,
    float* __restrict__ Hf, float* __restrict__ Hr)
{
    const int tid = threadIdx.x;
    const int b   = blockIdx.x & 63;
    const int dir = blockIdx.x >> 6;
    const float* wih = dir ? wih_r : wih_f;
    const float* whh = dir ? whh_r : whh_f;
    const float* bih = dir ? bih_r : bih_f;
    const float* bhh = dir ? bhh_r : bhh_f;
    float* Hout = dir ? Hr : Hf;

    __shared__ __align__(16) float h_lds[128];
    __shared__ float gates[512];
    __shared__ __align__(16) float x3[3][48];

    const int j = tid;
    float4 wr[32];
    {
        const float4* wp = reinterpret_cast<const float4*>(whh + j * 128);
#pragma unroll
        for (int m = 0; m < 32; ++m) wr[m] = wp[m];
    }
    float4 wx[10];
    {
        const float4* xp = reinterpret_cast<const float4*>(wih + j * 40);
#pragma unroll
        for (int q = 0; q < 10; ++q) wx[q] = xp[q];
    }
    const float bias = bih[j] + bhh[j];
    float c = 0.0f;
    if (tid < 128) h_lds[tid] = 0.0f;
    if (tid < 40) {
        int tt0 = dir ? 2047 : 0;
        x3[0][tid] = utter[((size_t)b * 2048 + tt0) * 40 + tid];
    } else if (tid < 80) {
        int tt1 = dir ? 2046 : 1;
        x3[1][tid - 40] = utter[((size_t)b * 2048 + tt1) * 40 + (tid - 40)];
    }
    __syncthreads();

    for (int t = 0; t < 2048; ++t) {
        const int cur = t % 3;
        const int nx2 = (t + 2) % 3;
        float xn = 0.0f;
        const int tq = tid - 128;
        if (tq >= 0 && tq < 40) {
            int tn = (t + 2 < 2048) ? (t + 2) : 2047;
            int ttn = dir ? (2047 - tn) : tn;
            xn = utter[((size_t)b * 2048 + ttn) * 40 + tq];  // prefetch depth-2
        }
        float g = bias;
        const float4* x4 = reinterpret_cast<const float4*>(&x3[cur][0]);
#pragma unroll
        for (int q = 0; q < 10; ++q) {
            float4 x = x4[q];
            g += wx[q].x * x.x + wx[q].y * x.y + wx[q].z * x.z + wx[q].w * x.w;
        }
        const float4* h4 = reinterpret_cast<const float4*>(h_lds);
#pragma unroll
        for (int m = 0; m < 32; ++m) {
            float4 h = h4[m];
            g += wr[m].x * h.x + wr[m].y * h.y + wr[m].z * h.z + wr[m].w * h.w;
        }
        gates[j] = g;
        __syncthreads();
        if (tid < 128) {
            float i_ = sigm(gates[tid]);
            float f_ = sigm(gates[128 + tid]);
            float g_ = tanh_(gates[256 + tid]);
            float o_ = sigm(gates[384 + tid]);
            c = f_ * c + i_ * g_;
            float hh = o_ * tanh_(c);
            h_lds[tid] = hh;
            int tt = dir ? (2047 - t) : t;
            Hout[((size_t)tt * 64 + b) * 128 + tid] = hh;
        } else if (tq < 40) {
            x3[nx2][tq] = xn;
        }
        __syncthreads();
    }
}

// ---------------- LSTM layers 2/3 (P precomputed incl. biases) ----------------
__global__ __launch_bounds__(512, 2) void lstm_k(
    const float* __restrict__ P, const float* __restrict__ whh,
    float* __restrict__ Hout, int T)
{
    const int tid = threadIdx.x;
    const int b = blockIdx.x;
    const int j = tid;
    __shared__ __align__(16) float h_lds[128];
    __shared__ float gates[512];
    float4 wr[32];
    {
        const float4* wp = reinterpret_cast<const float4*>(whh + j * 128);
#pragma unroll
        for (int m = 0; m < 32; ++m) wr[m] = wp[m];
    }
    float c = 0.0f;
    if (tid < 128) h_lds[tid] = 0.0f;
    float p_cur = P[((size_t)b * T + 0) * 512 + j];
    float p_n1  = P[((size_t)b * T + ((T > 1) ? 1 : 0)) * 512 + j];
    __syncthreads();
    for (int t = 0; t < T; ++t) {
        int tn = (t + 2 < T) ? (t + 2) : (T - 1);
        float p_n2 = P[((size_t)b * T + tn) * 512 + j];  // prefetch depth-2
        float g = p_cur;
        const float4* h4 = reinterpret_cast<const float4*>(h_lds);
#pragma unroll
        for (int m = 0; m < 32; ++m) {
            float4 h = h4[m];
            g += wr[m].x * h.x + wr[m].y * h.y + wr[m].z * h.z + wr[m].w * h.w;
        }
        gates[j] = g;
        __syncthreads();
        if (tid < 128) {
            float i_ = sigm(gates[tid]);
            float f_ = sigm(gates[128 + tid]);
            float g_ = tanh_(gates[256 + tid]);
            float o_ = sigm(gates[384 + tid]);
            c = f_ * c + i_ * g_;
            float hh = o_ * tanh_(c);
            h_lds[tid] = hh;
            Hout[((size_t)t * 64 + b) * 128 + tid] = hh;
        }
        __syncthreads();
        p_cur = p_n1;
        p_n1 = p_n2;
    }
}

// ---------------- conv1d kernel=2 stride=2 (as feature-pair dot) ----------------
template <int CIN>
__global__ __launch_bounds__(128) void conv_k(
    const float* __restrict__ HA, const float* __restrict__ HB,
    const float* __restrict__ W, const float* __restrict__ bias,
    float* __restrict__ out, int Tout)
{
    __shared__ __align__(16) float xin[64 * CIN];
    const int b = blockIdx.x;
    const int t0 = blockIdx.y * 32;
    const int tid = threadIdx.x;
    for (int idx = tid; idx < 64 * CIN; idx += 128) {
        int tl = idx / CIN, ci = idx % CIN;
        int tau = t0 * 2 + tl;
        float v;
        if constexpr (CIN == 256) {
            v = (ci < 128) ? HA[(size_t)tau * 8192 + b * 128 + ci]
                           : HB[(size_t)tau * 8192 + b * 128 + (ci - 128)];
        } else {
            v = HA[(size_t)tau * 8192 + b * 128 + ci];
        }
        xin[idx] = v;
    }
    __syncthreads();
    const int co = tid;
    float acc[32];
#pragma unroll
    for (int u = 0; u < 32; ++u) acc[u] = 0.0f;
    const float4* Wrow4 = reinterpret_cast<const float4*>(W + (size_t)co * 2 * CIN);
    const float4* xin4 = reinterpret_cast<const float4*>(xin);
    for (int c4 = 0; c4 < CIN / 4; ++c4) {
        float4 wA = Wrow4[2 * c4];
        float4 wB = Wrow4[2 * c4 + 1];
#pragma unroll
        for (int u = 0; u < 32; ++u) {
            float4 x0 = xin4[(2 * u) * (CIN / 4) + c4];
            float4 x1 = xin4[(2 * u + 1) * (CIN / 4) + c4];
            acc[u] += wA.x * x0.x + wA.y * x1.x + wA.z * x0.y + wA.w * x1.y
                    + wB.x * x0.z + wB.y * x1.z + wB.z * x0.w + wB.w * x1.w;
        }
    }
    float bs = bias[co];
#pragma unroll
    for (int u = 0; u < 32; ++u)
        out[((size_t)b * Tout + t0 + u) * 128 + co] = acc[u] + bs;
}

// ---------------- generic f32 GEMM: C[m,n] = sum_k A[m,k]*W[n,k] + b1[n] + b2[n] ----------------
__global__ __launch_bounds__(256) void gemm_k(
    const float* __restrict__ A, const float* __restrict__ W, int ldw,
    const float* __restrict__ bias1, const float* __restrict__ bias2,
    float* __restrict__ C, int M, int N, int K, int mode, int Tdim)
{
    __shared__ __align__(16) float As[16][68];
    __shared__ __align__(16) float Ws[16][68];
    const int tid = threadIdx.x;
    const int m0 = blockIdx.x * 64, n0 = blockIdx.y * 64;
    const int kk = tid & 15, mm = tid >> 4;
    const int tm = tid & 15, tn = tid >> 4;
    float acc[4][4];
#pragma unroll
    for (int i = 0; i < 4; ++i)
#pragma unroll
        for (int jj = 0; jj < 4; ++jj) acc[i][jj] = 0.0f;

    for (int k0 = 0; k0 < K; k0 += 16) {
#pragma unroll
        for (int r = 0; r < 4; ++r) {
            As[kk][mm + 16 * r] = A[(size_t)(m0 + mm + 16 * r) * K + k0 + kk];
            Ws[kk][mm + 16 * r] = W[(size_t)(n0 + mm + 16 * r) * ldw + k0 + kk];
        }
        __syncthreads();
#pragma unroll
        for (int q = 0; q < 16; ++q) {
            float4 a = reinterpret_cast<const float4*>(&As[q][0])[tm];
            float4 w = reinterpret_cast<const float4*>(&Ws[q][0])[tn];
            acc[0][0] += a.x * w.x; acc[0][1] += a.x * w.y; acc[0][2] += a.x * w.z; acc[0][3] += a.x * w.w;
            acc[1][0] += a.y * w.x; acc[1][1] += a.y * w.y; acc[1][2] += a.y * w.z; acc[1][3] += a.y * w.w;
            acc[2][0] += a.z * w.x; acc[2][1] += a.z * w.y; acc[2][2] += a.z * w.z; acc[2][3] += a.z * w.w;
            acc[3][0] += a.w * w.x; acc[3][1] += a.w * w.y; acc[3][2] += a.w * w.z; acc[3][3] += a.w * w.w;
        }
        __syncthreads();
    }
    float bv[4];
#pragma unroll
    for (int jj = 0; jj < 4; ++jj) {
        int n = n0 + tn * 4 + jj;
        float v = 0.0f;
        if (bias1) v += bias1[n];
        if (bias2) v += bias2[n];
        bv[jj] = v;
    }
#pragma unroll
    for (int i = 0; i < 4; ++i) {
        int m = m0 + tm * 4 + i;
#pragma unroll
        for (int jj = 0; jj < 4; ++jj) {
            int n = n0 + tn * 4 + jj;
            float v = acc[i][jj] + bv[jj];
            if (mode == 0) {
                C[(size_t)m * N + n] = v;
            } else {
                int bb = m & 63, tt = m >> 6;
                C[((size_t)bb * N + n) * Tdim + tt] = v;
            }
        }
    }
}

// ---------------- gather emb[targets] rows: Ypack[(l*64+b)][e] ----------------
__global__ __launch_bounds__(512) void packemb_k(
    const int* __restrict__ targets, const float* __restrict__ emb,
    float* __restrict__ Ypack)
{
    int m = blockIdx.x;  // l*64 + b
    int l = m >> 6, b = m & 63;
    int tgt = targets[b * 256 + l];
    Ypack[(size_t)m * 512 + threadIdx.x] = emb[(size_t)tgt * 512 + threadIdx.x];
}

// ---------------- attention decoder: one WG per batch, 255 steps ----------------
// Per-step operands fully on-chip: whhd row f32 in regs (128), hk row bf16 in
// regs (64), wc2 bf16 in LDS (128 KiB). hv read from L2 with 4-acc MLP.
__global__ __launch_bounds__(512, 2) void decoder_k(
    const float* __restrict__ Yp, const float* __restrict__ whhd, const float* __restrict__ wihd,
    const float* __restrict__ hk, const float* __restrict__ hv,
    const float* __restrict__ w1, const float* __restrict__ b1,
    const float* __restrict__ w2, const float* __restrict__ b2,
    const float* __restrict__ w3, const float* __restrict__ b3,
    const float* __restrict__ sh0, const float* __restrict__ sc0,
    float* __restrict__ out)
{
    __shared__ unsigned int wc2[64][512];  // 128 KiB: c-path weights, bf16 pairs, [k2][j]
    __shared__ __align__(16) float sh_lds[128];
    __shared__ __align__(16) float sc_lds[128];
    __shared__ __align__(16) float c_lds[128];
    __shared__ float gates[512];
    __shared__ float att[512];
    __shared__ float red[16];
    __shared__ float out_lds[34];
    __shared__ float z_lds[34];

    const int tid = threadIdx.x;
    const int b = blockIdx.x;
    const int j = tid;

    float4 wr[32];  // whhd row j (f32, 128 VGPRs)
    {
        const float4* wp = reinterpret_cast<const float4*>(whhd + j * 128);
#pragma unroll
        for (int m = 0; m < 32; ++m) wr[m] = wp[m];
    }
    for (int idx = tid; idx < 64 * 512; idx += 512) {
        int k2 = idx >> 9, jj = idx & 511;
        float a = wihd[(size_t)jj * 640 + 512 + 2 * k2];
        float bb2 = wihd[(size_t)jj * 640 + 512 + 2 * k2 + 1];
        wc2[k2][jj] = packbf2(a, bb2);
    }
    // hk row t=tid for batch b, packed bf16 (64 VGPRs). hk layout [t][b][d].
    unsigned int hkp[64];
    {
        const float4* hp = reinterpret_cast<const float4*>(hk + ((size_t)tid * 64 + b) * 128);
#pragma unroll
        for (int q = 0; q < 32; ++q) {
            float4 v = hp[q];
            hkp[2 * q]     = packbf2(v.x, v.y);
            hkp[2 * q + 1] = packbf2(v.z, v.w);
        }
    }
    float sc_r = 0.0f;
    if (tid < 128) {
        sh_lds[tid] = sh0[b * 128 + tid];
        sc_r = sc0[b * 128 + tid];
        sc_lds[tid] = sc_r;
        c_lds[tid] = 0.0f;
    }
    __syncthreads();

    const int wid = tid >> 6, lane = tid & 63;
    float yp_cur = Yp[(size_t)(0 * 64 + b) * 512 + j];
    for (int l = 0; l < 255; ++l) {
        int lnxt = (l + 1 < 255) ? (l + 1) : l;
        float yp_nxt = Yp[(size_t)(lnxt * 64 + b) * 512 + j];
        // ---- phase 1: gates = Yp + sh@whhd.T + c@wihd_c.T
        float g = yp_cur;
        const float4* sh4 = reinterpret_cast<const float4*>(sh_lds);
#pragma unroll
        for (int m = 0; m < 32; ++m) {
            float4 h = sh4[m];
            g += wr[m].x * h.x + wr[m].y * h.y + wr[m].z * h.z + wr[m].w * h.w;
        }
        const float2* c2 = reinterpret_cast<const float2*>(c_lds);
#pragma unroll
        for (int k2 = 0; k2 < 64; ++k2) {
            unsigned int u = wc2[k2][j];
            float2 cc = c2[k2];
            g += __uint_as_float(u << 16) * cc.x + __uint_as_float(u & 0xffff0000u) * cc.y;
        }
        gates[j] = g;
        __syncthreads();
        // ---- phase 2: cell update
        if (tid < 128) {
            float i_ = sigm(gates[tid]);
            float f_ = sigm(gates[128 + tid]);
            float g_ = tanh_(gates[256 + tid]);
            float o_ = sigm(gates[384 + tid]);
            sc_r = f_ * sc_r + i_ * g_;
            float hh = o_ * tanh_(sc_r);
            sh_lds[tid] = hh;
            sc_lds[tid] = sc_r;
        }
        __syncthreads();
        // ---- phase 3: attention scores from registers (thread t = position)
        float e = 0.0f;
        {
            const float2* sc2 = reinterpret_cast<const float2*>(sc_lds);
#pragma unroll
            for (int d2 = 0; d2 < 64; ++d2) {
                unsigned int u = hkp[d2];
                float2 s = sc2[d2];
                e += __uint_as_float(u << 16) * s.x + __uint_as_float(u & 0xffff0000u) * s.y;
            }
        }
        float em = e;
#pragma unroll
        for (int off = 32; off; off >>= 1) em = fmaxf(em, __shfl_xor(em, off));
        if (lane == 0) red[wid] = em;
        __syncthreads();
        float mx = red[0];
#pragma unroll
        for (int w = 1; w < 8; ++w) mx = fmaxf(mx, red[w]);
        float p = __expf(e - mx);
        float ps = p;
#pragma unroll
        for (int off = 32; off; off >>= 1) ps += __shfl_xor(ps, off);
        if (lane == 0) red[8 + wid] = ps;
        __syncthreads();
        float S = red[8];
#pragma unroll
        for (int w = 1; w < 8; ++w) S += red[8 + w];
        att[tid] = p / S;
        __syncthreads();
        // ---- phase 4: context c_n = att @ hv (hv layout [t][b][d], L2-resident)
        {
            int g4 = tid >> 7, d = tid & 127;
            const float* hvp = hv + (size_t)b * 128 + d;
            float a0 = 0.f, a1 = 0.f, a2 = 0.f, a3 = 0.f;
            int tbase = g4 * 128;
#pragma unroll 8
            for (int tt = 0; tt < 128; tt += 4) {
                a0 += att[tbase + tt]     * hvp[(size_t)(tbase + tt)     * 8192];
                a1 += att[tbase + tt + 1] * hvp[(size_t)(tbase + tt + 1) * 8192];
                a2 += att[tbase + tt + 2] * hvp[(size_t)(tbase + tt + 2) * 8192];
                a3 += att[tbase + tt + 3] * hvp[(size_t)(tbase + tt + 3) * 8192];
            }
            gates[tid] = (a0 + a1) + (a2 + a3);
        }
        __syncthreads();
        if (tid < 128)
            c_lds[tid] = gates[tid] + gates[128 + tid] + gates[256 + tid] + gates[384 + tid];
        __syncthreads();
        // ---- phase 5: output head
        if (tid < 34) {
            float o1 = b1[tid] + b2[tid];
            const float* w1r = w1 + tid * 128;
            const float* w2r = w2 + tid * 128;
#pragma unroll 4
            for (int d = 0; d < 128; ++d) o1 += sh_lds[d] * w1r[d] + c_lds[d] * w2r[d];
            out_lds[tid] = fmaxf(o1, 0.0f);
        }
        __syncthreads();
        if (tid < 34) {
            float z = b3[tid];
            const float* w3r = w3 + tid * 34;
            for (int v = 0; v < 34; ++v) z += out_lds[v] * w3r[v];
            z_lds[tid] = z;
        }
        __syncthreads();
        if (tid < 34) {
            float zm = z_lds[0];
            for (int v = 1; v < 34; ++v) zm = fmaxf(zm, z_lds[v]);
            float Ssum = 0.0f;
            for (int v = 0; v < 34; ++v) Ssum += __expf(z_lds[v] - zm);
            out[((size_t)b * 255 + l) * 34 + tid] = __expf(z_lds[tid] - zm) / Ssum;
        }
        yp_cur = yp_nxt;
        __syncthreads();
    }
}

// ---------------- launch ----------------
extern "C" void kernel_launch(void* const* d_in, const int* in_sizes, int n_in,
                              void* d_out, int out_size, void* d_ws, size_t ws_size,
                              hipStream_t stream) {
    (void)in_sizes; (void)n_in; (void)out_size; (void)ws_size;
    const float* utter = (const float*)d_in[0];
    const int*   targets = (const int*)d_in[1];
    const float* wih_f = (const float*)d_in[2];
    const float* whh_f = (const float*)d_in[3];
    const float* bih_f = (const float*)d_in[4];
    const float* bhh_f = (const float*)d_in[5];
    const float* wih_r = (const float*)d_in[6];
    const float* whh_r = (const float*)d_in[7];
    const float* bih_r = (const float*)d_in[8];
    const float* bhh_r = (const float*)d_in[9];
    const float* c1w = (const float*)d_in[10];
    const float* c1b = (const float*)d_in[11];
    const float* wih1 = (const float*)d_in[12];
    const float* whh1 = (const float*)d_in[13];
    const float* bih1 = (const float*)d_in[14];
    const float* bhh1 = (const float*)d_in[15];
    const float* c2w = (const float*)d_in[16];
    const float* c2b = (const float*)d_in[17];
    const float* wih2 = (const float*)d_in[18];
    const float* whh2 = (const float*)d_in[19];
    const float* bih2 = (const float*)d_in[20];
    const float* bhh2 = (const float*)d_in[21];
    const float* kw = (const float*)d_in[22];
    const float* kb = (const float*)d_in[23];
    const float* vw = (const float*)d_in[24];
    const float* vb = (const float*)d_in[25];
    const float* wihd = (const float*)d_in[26];
    const float* whhd = (const float*)d_in[27];
    const float* bihd = (const float*)d_in[28];
    const float* bhhd = (const float*)d_in[29];
    const float* w1 = (const float*)d_in[30];
    const float* b1 = (const float*)d_in[31];
    const float* w2 = (const float*)d_in[32];
    const float* b2 = (const float*)d_in[33];
    const float* w3 = (const float*)d_in[34];
    const float* b3 = (const float*)d_in[35];
    const float* emb = (const float*)d_in[36];
    const float* sh0 = (const float*)d_in[37];
    const float* sc0 = (const float*)d_in[38];

    // ---- workspace plan, peak 160 MiB (phase-based reuse, stream-ordered) ----
    char* ws = (char*)d_ws;
    const size_t MB = 1ull << 20;
    float* Hf       = (float*)(ws + 0);         // 64 MiB  [t][b][128]
    float* Hr       = (float*)(ws + 64 * MB);   // 64 MiB  [t][b][128]
    float* conv1out = (float*)(ws + 128 * MB);  // 32 MiB  [b][t'][128]
    float* P2       = (float*)(ws + 0);         // 128 MiB [b][t'][512]   (over Hf+Hr)
    float* H2       = (float*)(ws + 128 * MB);  // 32 MiB  [t][b][128]    (over conv1out)
    float* conv2out = (float*)(ws + 0);         // 16 MiB  [b][t''][128]  (over P2 head)
    float* P3       = (float*)(ws + 16 * MB);   // 64 MiB  [b][t''][512]
    float* H3       = (float*)(ws + 80 * MB);   // 16 MiB  [t''][b][128]
    float* hkb      = (float*)(ws + 96 * MB);   // 16 MiB  [t''][b][d]
    float* hvb      = (float*)(ws + 112 * MB);  // 16 MiB  [t''][b][d]
    float* Ypack    = (float*)(ws + 128 * MB);  // 32 MiB  (over H2, dead after conv2)
    float* Yp       = (float*)(ws + 0);         // 32 MiB  (over conv2out+P3 head, dead after lstm3)

    // encoder layer 1 (bidirectional, fused input proj)
    lstm1_k<<<128, 512, 0, stream>>>(utter, wih_f, whh_f, bih_f, bhh_f,
                                     wih_r, whh_r, bih_r, bhh_r, Hf, Hr);
    // conv1: 256ch -> 128ch, T 2048 -> 1024
    conv_k<256><<<dim3(64, 32), 128, 0, stream>>>(Hf, Hr, c1w, c1b, conv1out, 1024);
    // input proj for lstm2 (writes over Hf/Hr, reads conv1out)
    gemm_k<<<dim3(1024, 8), 256, 0, stream>>>(conv1out, wih1, 128, bih1, bhh1,
                                              P2, 65536, 512, 128, 0, 0);
    lstm_k<<<64, 512, 0, stream>>>(P2, whh1, H2, 1024);
    // conv2: 128ch -> 128ch, T 1024 -> 512 (writes over P2 head, reads H2)
    conv_k<128><<<dim3(64, 16), 128, 0, stream>>>(H2, nullptr, c2w, c2b, conv2out, 512);
    gemm_k<<<dim3(512, 8), 256, 0, stream>>>(conv2out, wih2, 128, bih2, bhh2,
                                             P3, 32768, 512, 128, 0, 0);
    lstm_k<<<64, 512, 0, stream>>>(P3, whh2, H3, 512);
    // hk, hv: both [t''][b][d] (mode 0 over m=(t*64+b))
    gemm_k<<<dim3(512, 2), 256, 0, stream>>>(H3, kw, 128, kb, nullptr,
                                             hkb, 32768, 128, 128, 0, 0);
    gemm_k<<<dim3(512, 2), 256, 0, stream>>>(H3, vw, 128, vb, nullptr,
                                             hvb, 32768, 128, 128, 0, 0);
    // decoder y-path projection (sequentially dead -> hoisted); Ypack over H2 (dead)
    packemb_k<<<16320, 512, 0, stream>>>(targets, emb, Ypack);
    gemm_k<<<dim3(255, 8), 256, 0, stream>>>(Ypack, wihd, 640, bihd, bhhd,
                                             Yp, 16320, 512, 512, 0, 0);
    // attention decoder
    decoder_k<<<64, 512, 0, stream>>>(Yp, whhd, wihd, hkb, hvb,
                                      w1, b1, w2, b2, w3, b3, sh0, sc0,
                                      (float*)d_out);
}